// Round 5
// baseline (193.893 us; speedup 1.0000x reference)
//
#include <hip/hip_runtime.h>

// Problem shapes (fixed by reference setup_inputs)
#define B_DIM 1024
#define C_DIM 128
#define K_DIM 1024
#define E_DIM 4
#define EMBED_ELEMS (B_DIM * C_DIM * E_DIM)

// ---------------------------------------------------------------------------
// K1: argmin + embed. One block = 4 waves, same c; each wave owns 8 b-rows.
// Grid = C * (B/32) = 4096 blocks. Writes idx (B,C) int32 and embed (B,C,4).
// ---------------------------------------------------------------------------
__global__ __launch_bounds__(256) void vq_argmin_kernel(
    const float* __restrict__ cw_q,      // (B, C*E) f32
    const float* __restrict__ codebook,  // (C, K, E) f32
    float* __restrict__ out,             // embed at offset 0
    int* __restrict__ idx_out)           // (B, C) int32 in d_ws
{
    __shared__ float4 lds_cb[K_DIM];     // 16 KB: codebook[c]

    const int lane = threadIdx.x & 63;
    const int wave = threadIdx.x >> 6;
    const int bid  = blockIdx.x;
    const int c      = bid >> 5;         // 32 blocks per c
    const int btile  = bid & 31;
    const int b_base = btile * 32 + wave * 8;

    const float4* cb4 = (const float4*)codebook + (size_t)c * K_DIM;
    const float4* x4  = (const float4*)cw_q;    // (B, C) float4
    float4* emb4 = (float4*)out;                // (B, C) float4

    for (int t = threadIdx.x; t < K_DIM; t += 256)
        lds_cb[t] = cb4[t];
    __syncthreads();

    // ||b_k||^2 in f64 (exact from f32 inputs -> true ordering, proven R3/R4).
    double bsq[16];
#pragma unroll
    for (int j = 0; j < 16; ++j) {
        const float4 cb = lds_cb[j * 64 + lane];
        const double bx = (double)cb.x, by = (double)cb.y,
                     bz = (double)cb.z, bw = (double)cb.w;
        bsq[j] = bx * bx + by * by + bz * bz + bw * bw;
    }

    for (int g = 0; g < 2; ++g) {
        double x2[4][4];
#pragma unroll
        for (int ii = 0; ii < 4; ++ii) {
            const int b = b_base + g * 4 + ii;
            const float4 x = x4[(size_t)b * C_DIM + c];
            x2[ii][0] = -2.0 * (double)x.x;
            x2[ii][1] = -2.0 * (double)x.y;
            x2[ii][2] = -2.0 * (double)x.z;
            x2[ii][3] = -2.0 * (double)x.w;
        }

        double bestd[4];
        int    bestk[4];
#pragma unroll
        for (int ii = 0; ii < 4; ++ii) { bestd[ii] = INFINITY; bestk[ii] = 0x7fffffff; }

        for (int j = 0; j < 16; ++j) {
            const float4 cb = lds_cb[j * 64 + lane];
            const double bx = (double)cb.x, by = (double)cb.y,
                         bz = (double)cb.z, bw = (double)cb.w;
            const int k = j * 64 + lane;
#pragma unroll
            for (int ii = 0; ii < 4; ++ii) {
                // d' = bsq - 2*dot  (x_sq constant over k: argmin-invariant)
                const double d = fma(bw, x2[ii][3],
                                 fma(bz, x2[ii][2],
                                 fma(by, x2[ii][1],
                                 fma(bx, x2[ii][0], bsq[j]))));
                if (d < bestd[ii]) { bestd[ii] = d; bestk[ii] = k; }
            }
        }

        // Wave argmin, lexicographic (d, k), 4 rows interleaved.
#pragma unroll
        for (int off = 32; off >= 1; off >>= 1) {
#pragma unroll
            for (int ii = 0; ii < 4; ++ii) {
                const double od = __shfl_xor(bestd[ii], off);
                const int    oi = __shfl_xor(bestk[ii], off);
                if (od < bestd[ii] || (od == bestd[ii] && oi < bestk[ii])) {
                    bestd[ii] = od; bestk[ii] = oi;
                }
            }
        }

#pragma unroll
        for (int ii = 0; ii < 4; ++ii) {
            const int b  = b_base + g * 4 + ii;
            const int bi = bestk[ii];
            if (lane == 0) {
                emb4[(size_t)b * C_DIM + c] = lds_cb[bi];
                idx_out[b * C_DIM + c]      = bi;
            }
        }
    }
}

// ---------------------------------------------------------------------------
// K2: one-hot fill. One block per b writes its contiguous 512 KB slab
// (pure streaming, memset-like), patching the 1s from LDS-cached indices.
// ---------------------------------------------------------------------------
__global__ __launch_bounds__(256) void vq_onehot_kernel(
    const int* __restrict__ idx_in,      // (B, C)
    float* __restrict__ out)             // one_hot at EMBED_ELEMS
{
    __shared__ int sidx[C_DIM];
    const int b   = blockIdx.x;
    const int tid = threadIdx.x;
    if (tid < C_DIM) sidx[tid] = idx_in[b * C_DIM + tid];
    __syncthreads();

    float4* slab = (float4*)(out + EMBED_ELEMS + (size_t)b * C_DIM * K_DIM);
    const int k0 = tid * 4;
#pragma unroll 4
    for (int i = 0; i < C_DIM; ++i) {       // i == c; 4 KB per iteration
        const int t = sidx[i];              // LDS broadcast (uniform address)
        float4 v;
        v.x = (k0 + 0 == t) ? 1.0f : 0.0f;
        v.y = (k0 + 1 == t) ? 1.0f : 0.0f;
        v.z = (k0 + 2 == t) ? 1.0f : 0.0f;
        v.w = (k0 + 3 == t) ? 1.0f : 0.0f;
        slab[i * 256 + tid] = v;
    }
}

extern "C" void kernel_launch(void* const* d_in, const int* in_sizes, int n_in,
                              void* d_out, int out_size, void* d_ws, size_t ws_size,
                              hipStream_t stream) {
    const float* cw_q     = (const float*)d_in[0];
    const float* codebook = (const float*)d_in[1];
    float* out = (float*)d_out;
    int*   idx = (int*)d_ws;   // 512 KB scratch

    vq_argmin_kernel<<<C_DIM * (B_DIM / 32), 256, 0, stream>>>(cw_q, codebook, out, idx);
    vq_onehot_kernel<<<B_DIM, 256, 0, stream>>>(idx, out);
}

// Round 7
// 186.652 us; speedup vs baseline: 1.0388x; 1.0388x over previous
//
#include <hip/hip_runtime.h>

// Problem shapes (fixed by reference setup_inputs)
#define B_DIM 1024
#define C_DIM 128
#define K_DIM 1024
#define E_DIM 4
#define EMBED_ELEMS (B_DIM * C_DIM * E_DIM)

typedef float f32x4 __attribute__((ext_vector_type(4)));

// ---------------------------------------------------------------------------
// K1: argmin + embed (unchanged, proven exact). One block = 4 waves, same c;
// each wave owns 8 b-rows. Grid = 4096 blocks. Writes idx (B,C) i32 + embed.
// ---------------------------------------------------------------------------
__global__ __launch_bounds__(256) void vq_argmin_kernel(
    const float* __restrict__ cw_q,      // (B, C*E) f32
    const float* __restrict__ codebook,  // (C, K, E) f32
    float* __restrict__ out,             // embed at offset 0
    int* __restrict__ idx_out)           // (B, C) int32 in d_ws
{
    __shared__ float4 lds_cb[K_DIM];     // 16 KB: codebook[c]

    const int lane = threadIdx.x & 63;
    const int wave = threadIdx.x >> 6;
    const int bid  = blockIdx.x;
    const int c      = bid >> 5;         // 32 blocks per c
    const int btile  = bid & 31;
    const int b_base = btile * 32 + wave * 8;

    const float4* cb4 = (const float4*)codebook + (size_t)c * K_DIM;
    const float4* x4  = (const float4*)cw_q;    // (B, C) float4
    float4* emb4 = (float4*)out;                // (B, C) float4

    for (int t = threadIdx.x; t < K_DIM; t += 256)
        lds_cb[t] = cb4[t];
    __syncthreads();

    // ||b_k||^2 in f64 (exact from f32 inputs -> true ordering, proven R3/R4).
    double bsq[16];
#pragma unroll
    for (int j = 0; j < 16; ++j) {
        const float4 cb = lds_cb[j * 64 + lane];
        const double bx = (double)cb.x, by = (double)cb.y,
                     bz = (double)cb.z, bw = (double)cb.w;
        bsq[j] = bx * bx + by * by + bz * bz + bw * bw;
    }

    for (int g = 0; g < 2; ++g) {
        double x2[4][4];
#pragma unroll
        for (int ii = 0; ii < 4; ++ii) {
            const int b = b_base + g * 4 + ii;
            const float4 x = x4[(size_t)b * C_DIM + c];
            x2[ii][0] = -2.0 * (double)x.x;
            x2[ii][1] = -2.0 * (double)x.y;
            x2[ii][2] = -2.0 * (double)x.z;
            x2[ii][3] = -2.0 * (double)x.w;
        }

        double bestd[4];
        int    bestk[4];
#pragma unroll
        for (int ii = 0; ii < 4; ++ii) { bestd[ii] = INFINITY; bestk[ii] = 0x7fffffff; }

        for (int j = 0; j < 16; ++j) {
            const float4 cb = lds_cb[j * 64 + lane];
            const double bx = (double)cb.x, by = (double)cb.y,
                         bz = (double)cb.z, bw = (double)cb.w;
            const int k = j * 64 + lane;
#pragma unroll
            for (int ii = 0; ii < 4; ++ii) {
                // d' = bsq - 2*dot  (x_sq constant over k: argmin-invariant)
                const double d = fma(bw, x2[ii][3],
                                 fma(bz, x2[ii][2],
                                 fma(by, x2[ii][1],
                                 fma(bx, x2[ii][0], bsq[j]))));
                if (d < bestd[ii]) { bestd[ii] = d; bestk[ii] = k; }
            }
        }

        // Wave argmin, lexicographic (d, k), 4 rows interleaved.
#pragma unroll
        for (int off = 32; off >= 1; off >>= 1) {
#pragma unroll
            for (int ii = 0; ii < 4; ++ii) {
                const double od = __shfl_xor(bestd[ii], off);
                const int    oi = __shfl_xor(bestk[ii], off);
                if (od < bestd[ii] || (od == bestd[ii] && oi < bestk[ii])) {
                    bestd[ii] = od; bestk[ii] = oi;
                }
            }
        }

#pragma unroll
        for (int ii = 0; ii < 4; ++ii) {
            const int b  = b_base + g * 4 + ii;
            const int bi = bestk[ii];
            if (lane == 0) {
                emb4[(size_t)b * C_DIM + c] = lds_cb[bi];
                idx_out[b * C_DIM + c]      = bi;   // cached store: K2 reads it
            }
        }
    }
}

// ---------------------------------------------------------------------------
// K2: one-hot fill with NON-TEMPORAL stores (bypass L2 write-allocate).
// Grid = B*4 = 4096 blocks; each block streams a contiguous 128 KB slab
// (32 c-rows of one b). Monotonic addresses, dwordx4 nt stores.
// ---------------------------------------------------------------------------
__global__ __launch_bounds__(256) void vq_onehot_kernel(
    const int* __restrict__ idx_in,      // (B, C)
    float* __restrict__ out)             // one_hot at EMBED_ELEMS
{
    __shared__ int sidx[32];
    const int b   = blockIdx.x >> 2;
    const int cq  = blockIdx.x & 3;      // quarter of the c range
    const int tid = threadIdx.x;
    if (tid < 32) sidx[tid] = idx_in[b * C_DIM + cq * 32 + tid];
    __syncthreads();

    f32x4* slab = (f32x4*)(out + EMBED_ELEMS
                           + ((size_t)b * C_DIM + cq * 32) * K_DIM);
    const int k0 = tid * 4;
#pragma unroll 4
    for (int i = 0; i < 32; ++i) {       // 4 KB per iteration, contiguous
        const int t = sidx[i];           // LDS broadcast (uniform address)
        f32x4 v;
        v.x = (k0 + 0 == t) ? 1.0f : 0.0f;
        v.y = (k0 + 1 == t) ? 1.0f : 0.0f;
        v.z = (k0 + 2 == t) ? 1.0f : 0.0f;
        v.w = (k0 + 3 == t) ? 1.0f : 0.0f;
        __builtin_nontemporal_store(v, &slab[i * 256 + tid]);
    }
}

extern "C" void kernel_launch(void* const* d_in, const int* in_sizes, int n_in,
                              void* d_out, int out_size, void* d_ws, size_t ws_size,
                              hipStream_t stream) {
    const float* cw_q     = (const float*)d_in[0];
    const float* codebook = (const float*)d_in[1];
    float* out = (float*)d_out;
    int*   idx = (int*)d_ws;   // 512 KB scratch

    vq_argmin_kernel<<<C_DIM * (B_DIM / 32), 256, 0, stream>>>(cw_q, codebook, out, idx);
    vq_onehot_kernel<<<B_DIM * 4, 256, 0, stream>>>(idx, out);
}